// Round 11
// baseline (621.649 us; speedup 1.0000x reference)
//
#include <hip/hip_runtime.h>

#define D_MODEL 4544
#define E_QKV   4672     // D + 2*64
#define E_STR   4736     // fused row stride & QKV weight row pad (37*128)
#define D_PAD   4608     // dense weight rows padded (36*128)
#define NH      71
#define SEQ     1024
#define NB      2
#define M_ROWS  2048     // NB*SEQ

typedef __bf16 bf16_t;
typedef bf16_t bf16x8 __attribute__((ext_vector_type(8)));
typedef float f32x4 __attribute__((ext_vector_type(4)));
typedef float f32x16 __attribute__((ext_vector_type(16)));
typedef unsigned u32x4 __attribute__((ext_vector_type(4)));

typedef __attribute__((address_space(1))) const void* gas_ptr;
typedef __attribute__((address_space(3))) void* las_ptr;

static __device__ __forceinline__ unsigned short f2bf(float f) {
  union { float f; unsigned u; } v; v.f = f;
  unsigned r = (v.u + 0x7fffu + ((v.u >> 16) & 1u)) >> 16;
  return (unsigned short)r;
}

static __device__ __forceinline__ unsigned cvtpk_bf16(float lo, float hi) {
  unsigned r;
  asm("v_cvt_pk_bf16_f32 %0, %1, %2" : "=v"(r) : "v"(lo), "v"(hi));
  return r;
}

static __device__ __forceinline__ float fast_exp2(float x) {
  float r;
  asm("v_exp_f32 %0, %1" : "=v"(r) : "v"(x));
  return r;
}

// dst[rows_pad][cols] bf16 <- src[rows_src][cols] f32, pad rows zeroed.
__global__ void convert_pad(const float* __restrict__ src, unsigned short* __restrict__ dst,
                            int rows_src, int rows_pad, int cols) {
  int idx = blockIdx.x * 256 + threadIdx.x;
  int cols4 = cols >> 2;
  int total = rows_pad * cols4;
  if (idx >= total) return;
  int row = idx / cols4;
  int c4 = (idx - row * cols4) << 2;
  ushort4 o;
  if (row < rows_src) {
    const float4 v = *(const float4*)(src + (size_t)row * cols + c4);
    o.x = f2bf(v.x); o.y = f2bf(v.y); o.z = f2bf(v.z); o.w = f2bf(v.w);
  } else {
    o.x = 0; o.y = 0; o.z = 0; o.w = 0;
  }
  *(ushort4*)(dst + (size_t)row * cols + c4) = o;
}

// ---------------- 128x128 GEMM, m97 2-barrier single-buffer structure ----------------
// 4 waves (2x2), BK=64, 32 KiB LDS -> ~4 blocks/CU co-resident (cross-block
// overlap does the pipelining — m97/m114 mechanism). LDS fragment-ordered:
// region(op,kh) = 8 KiB = 8 frag-blocks of 1 KiB; block fb holds rows
// fb*16..+15 x 32 k, lane-ordered -> every ds_read_b128 and every
// global_load_lds is a dense contiguous 1 KiB wave access (conflict-free).
#define RG(op_, kh_) ((((op_) * 2 + (kh_)) << 12))   // element offset (4096 elem = 8 KiB)

__global__ __launch_bounds__(256) void gemm128(
    const unsigned short* __restrict__ A,
    const unsigned short* __restrict__ B,
    float* __restrict__ C,
    int K, int Ntiles, int ldc, int Nact) {
  __shared__ __align__(16) unsigned short lds[16384];   // 32 KiB
  const int tid = threadIdx.x;
  const int wave = tid >> 6, lane = tid & 63;
  const int g = lane >> 4, c = lane & 15;
  const int wr = wave >> 1, wc = wave & 1;
  const int nwg = gridDim.x;
  const int swz = (blockIdx.x & 7) * (nwg >> 3) + (blockIdx.x >> 3);
  const int bm = swz / Ntiles, bn = swz - bm * Ntiles;
  const size_t bRow = (size_t)bm * 128, bCol = (size_t)bn * 128;
  const int NT = K >> 6;

  // per-lane staging base pointers (row part computed once)
  const unsigned short* pA = A + (bRow + (size_t)(wave * 16 + c)) * K + g * 8;
  const unsigned short* pB = B + (bCol + (size_t)(wave * 16 + c)) * K + g * 8;
  const int rowStep = 64 * K;   // element offset for frag-blocks 4..7

  f32x4 acc[4][4] = {};

  for (int t = 0; t < NT; ++t) {
    const int koff = t * 64;
    // stage tile t: 8 x global_load_lds (4 KiB each)
#pragma unroll
    for (int kh = 0; kh < 2; ++kh) {
#pragma unroll
      for (int ld2 = 0; ld2 < 2; ++ld2) {
        __builtin_amdgcn_global_load_lds((gas_ptr)(pA + ld2 * rowStep + koff + kh * 32),
            (las_ptr)(lds + RG(0, kh) + ((ld2 * 4 + wave) << 9)), 16, 0, 0);
        __builtin_amdgcn_global_load_lds((gas_ptr)(pB + ld2 * rowStep + koff + kh * 32),
            (las_ptr)(lds + RG(1, kh) + ((ld2 * 4 + wave) << 9)), 16, 0, 0);
      }
    }
    __syncthreads();
#pragma unroll
    for (int kh = 0; kh < 2; ++kh) {
      bf16x8 a[4], bv[4];
#pragma unroll
      for (int mm = 0; mm < 4; ++mm)
        a[mm] = *(const bf16x8*)&lds[RG(0, kh) + ((wr * 4 + mm) << 9) + lane * 8];
#pragma unroll
      for (int n = 0; n < 4; ++n)
        bv[n] = *(const bf16x8*)&lds[RG(1, kh) + ((wc * 4 + n) << 9) + lane * 8];
#pragma unroll
      for (int mm = 0; mm < 4; ++mm)
#pragma unroll
        for (int n = 0; n < 4; ++n)
          acc[mm][n] = __builtin_amdgcn_mfma_f32_16x16x32_bf16(a[mm], bv[n], acc[mm][n], 0, 0, 0);
    }
    __syncthreads();
  }

#pragma unroll
  for (int mm = 0; mm < 4; ++mm) {
#pragma unroll
    for (int n = 0; n < 4; ++n) {
      int col = (int)bCol + wc * 64 + n * 16 + c;
      if (col < Nact) {
#pragma unroll
        for (int r = 0; r < 4; ++r) {
          size_t row = bRow + wr * 64 + mm * 16 + g * 4 + r;
          C[row * ldc + col] = acc[mm][n][r];
        }
      }
    }
  }
}

// fused[n][l][E_STR] f32 -> Qb (RoPE, *0.125*log2e), Kb (RoPE), VTb (V^T)
__global__ void rope_extract(const float* __restrict__ fused,
                             unsigned short* __restrict__ Qb,
                             unsigned short* __restrict__ Kb,
                             unsigned short* __restrict__ VTb) {
  int idx = blockIdx.x * 256 + threadIdx.x;
  const int total = NB * SEQ * 73 * 64;
  if (idx >= total) return;
  int d = idx & 63;
  int t = idx >> 6;
  int h = t % 73;  t /= 73;
  int l = t & (SEQ - 1);
  int n = t >> 10;
  const float* frow = fused + ((size_t)(n * SEQ + l)) * E_STR + h * 64;
  float x = frow[d];
  if (h == 72) {
    VTb[((size_t)(n * 64 + d)) * SEQ + l] = f2bf(x);
    return;
  }
  int dh = d & 31;
  float inv = __expf(-(float)dh * (9.210340371976184f / 32.0f));
  float ang = (float)l * inv;
  float sn, cs;
  __sincosf(ang, &sn, &cs);
  float xr = frow[(d < 32) ? d + 32 : d - 32];
  float rh = (d < 32) ? -xr : xr;
  float out = x * cs + rh * sn;
  if (h == 71) {
    Kb[((size_t)(n * SEQ + l)) * 64 + d] = f2bf(out);
  } else {
    Qb[(((size_t)(n * NH + h)) * SEQ + l) * 64 + d] = f2bf(out * 0.1803368801111204f);
  }
}

// Swapped-QK^T flash MQA, per-wave causal pairing + K-prefetch + V-early-issue.
#define LOADK(dst_, ktv_) do {                                                 \
  _Pragma("unroll")                                                            \
  for (int _cc = 0; _cc < 4; ++_cc) {                                          \
    dst_[_cc]     = *(const bf16x8*)&kbase[(size_t)((ktv_) + c) * 64 + _cc * 16 + hi * 8];      \
    dst_[4 + _cc] = *(const bf16x8*)&kbase[(size_t)((ktv_) + 32 + c) * 64 + _cc * 16 + hi * 8]; \
  }                                                                            \
} while (0)

__global__ __launch_bounds__(128) void attn_kernel(
    const unsigned short* __restrict__ Qb,
    const unsigned short* __restrict__ Kb,
    const unsigned short* __restrict__ VTb,
    unsigned short* __restrict__ attnb) {
  const int h = blockIdx.y, n = blockIdx.z;
  const int wave = threadIdx.x >> 6, lane = threadIdx.x & 63;
  const int c = lane & 31, hi = lane >> 5;
  const int gw = blockIdx.x * 2 + wave;   // 0..15

  const unsigned short* kbase = Kb + (size_t)n * SEQ * 64;
  const unsigned short* vtbase = VTb + (size_t)n * 64 * SEQ;

  for (int pass = 0; pass < 2; ++pass) {
    const int tile = pass ? gw : (31 - gw);
    const int qrow0 = tile * 32;
    const int q = qrow0 + c;
    const int nk = qrow0 + 32;
    const unsigned short* qbase = Qb + (((size_t)(n * NH + h)) * SEQ + qrow0) * 64;

    bf16x8 qf[4];
#pragma unroll
    for (int cc = 0; cc < 4; ++cc)
      qf[cc] = *(const bf16x8*)&qbase[c * 64 + cc * 16 + hi * 8];

    f32x16 o0 = {}, o1 = {};
    float m_run = -1e30f, l_run = 0.f;

    bf16x8 kc[8], kn[8];
    LOADK(kc, 0);

    for (int kt = 0; kt < nk; kt += 64) {
      const bool more = (kt + 64) < nk;
      f32x16 s0 = {}, s1 = {};
#pragma unroll
      for (int cc = 0; cc < 4; ++cc) {
        s0 = __builtin_amdgcn_mfma_f32_32x32x16_bf16(kc[cc], qf[cc], s0, 0, 0, 0);
        s1 = __builtin_amdgcn_mfma_f32_32x32x16_bf16(kc[4 + cc], qf[cc], s1, 0, 0, 0);
      }
      if (more) LOADK(kn, kt + 64);
      bf16x8 vv0[4], vv1[4];
#pragma unroll
      for (int cg = 0; cg < 4; ++cg) {
        vv0[cg] = *(const bf16x8*)&vtbase[(size_t)c * SEQ + kt + cg * 16 + hi * 8];
        vv1[cg] = *(const bf16x8*)&vtbase[(size_t)(32 + c) * SEQ + kt + cg * 16 + hi * 8];
      }
      __builtin_amdgcn_sched_barrier(0);
      if (kt + 63 > qrow0) {
#pragma unroll
        for (int r = 0; r < 16; ++r) {
          const int key0 = kt + (r & 3) + 8 * (r >> 2) + 4 * hi;
          s0[r] = (key0 > q) ? -1e30f : s0[r];
          s1[r] = (key0 + 32 > q) ? -1e30f : s1[r];
        }
      }
      float tt[16];
#pragma unroll
      for (int r = 0; r < 16; ++r) tt[r] = fmaxf(s0[r], s1[r]);
#pragma unroll
      for (int st = 8; st > 0; st >>= 1)
#pragma unroll
        for (int r = 0; r < 8; ++r) if (r < st) tt[r] = fmaxf(tt[r], tt[r + st]);
      float mx = fmaxf(tt[0], __shfl_xor(tt[0], 32));
      const float mnew = fmaxf(m_run, mx);
      const float aa = fast_exp2(m_run - mnew);
#pragma unroll
      for (int r = 0; r < 16; ++r) {
        s0[r] = fast_exp2(s0[r] - mnew);
        s1[r] = fast_exp2(s1[r] - mnew);
      }
      float ps = 0.f;
#pragma unroll
      for (int r = 0; r < 16; ++r) ps += s0[r] + s1[r];
      ps += __shfl_xor(ps, 32);
      l_run = l_run * aa + ps;
      m_run = mnew;
#pragma unroll
      for (int r = 0; r < 16; ++r) { o0[r] *= aa; o1[r] *= aa; }

#pragma unroll
      for (int half = 0; half < 2; ++half) {
#pragma unroll
        for (int ccl = 0; ccl < 2; ++ccl) {
          const int cg = half * 2 + ccl;
          unsigned a0, a1, b0, b1;
          if (half == 0) {
            a0 = cvtpk_bf16(s0[8 * ccl + 0], s0[8 * ccl + 1]);
            a1 = cvtpk_bf16(s0[8 * ccl + 2], s0[8 * ccl + 3]);
            b0 = cvtpk_bf16(s0[8 * ccl + 4], s0[8 * ccl + 5]);
            b1 = cvtpk_bf16(s0[8 * ccl + 6], s0[8 * ccl + 7]);
          } else {
            a0 = cvtpk_bf16(s1[8 * ccl + 0], s1[8 * ccl + 1]);
            a1 = cvtpk_bf16(s1[8 * ccl + 2], s1[8 * ccl + 3]);
            b0 = cvtpk_bf16(s1[8 * ccl + 4], s1[8 * ccl + 5]);
            b1 = cvtpk_bf16(s1[8 * ccl + 6], s1[8 * ccl + 7]);
          }
          unsigned xa0 = __shfl_xor(a0, 32), xa1 = __shfl_xor(a1, 32);
          unsigned xb0 = __shfl_xor(b0, 32), xb1 = __shfl_xor(b1, 32);
          u32x4 fw;
          fw[0] = hi ? xb0 : a0;
          fw[1] = hi ? xb1 : a1;
          fw[2] = hi ? b0 : xa0;
          fw[3] = hi ? b1 : xa1;
          union { u32x4 u; bf16x8 b; } pf; pf.u = fw;
          o0 = __builtin_amdgcn_mfma_f32_32x32x16_bf16(vv0[cg], pf.b, o0, 0, 0, 0);
          o1 = __builtin_amdgcn_mfma_f32_32x32x16_bf16(vv1[cg], pf.b, o1, 0, 0, 0);
        }
      }
      if (more) {
#pragma unroll
        for (int cc = 0; cc < 8; ++cc) kc[cc] = kn[cc];
      }
    }

    const float inv = 1.0f / l_run;
    const size_t rowoff = (size_t)(n * SEQ + q) * D_MODEL + h * 64;
#pragma unroll
    for (int rr = 0; rr < 4; ++rr) {
      ushort4 w0, w1;
      w0.x = f2bf(o0[4 * rr + 0] * inv); w0.y = f2bf(o0[4 * rr + 1] * inv);
      w0.z = f2bf(o0[4 * rr + 2] * inv); w0.w = f2bf(o0[4 * rr + 3] * inv);
      w1.x = f2bf(o1[4 * rr + 0] * inv); w1.y = f2bf(o1[4 * rr + 1] * inv);
      w1.z = f2bf(o1[4 * rr + 2] * inv); w1.w = f2bf(o1[4 * rr + 3] * inv);
      *(ushort4*)&attnb[rowoff + 8 * rr + 4 * hi] = w0;
      *(ushort4*)&attnb[rowoff + 32 + 8 * rr + 4 * hi] = w1;
    }
  }
}

extern "C" void kernel_launch(void* const* d_in, const int* in_sizes, int n_in,
                              void* d_out, int out_size, void* d_ws, size_t ws_size,
                              hipStream_t stream) {
  const float* hs = (const float*)d_in[0];
  const float* wqkv = (const float*)d_in[1];
  const float* wdense = (const float*)d_in[2];
  float* out = (float*)d_out;
  char* ws = (char*)d_ws;

  unsigned short* hsb   = (unsigned short*)(ws + 0);            // 18,612,224
  unsigned short* wqkvb = (unsigned short*)(ws + 18612224);     // 4736*4544*2 = 43,044,864
  unsigned short* wdb   = (unsigned short*)(ws + 61657088);     // 4608*4544*2 = 41,881,600
  float*          fused = (float*)(ws + 103538688);             // 2048*4736*4 = 38,797,312
  unsigned short* qb    = (unsigned short*)(ws + 142336000);    // 18,612,224
  unsigned short* kb    = (unsigned short*)(ws + 160948224);    // 262,144
  unsigned short* vtb   = (unsigned short*)(ws + 161210368);    // 262,144
  unsigned short* attnb = (unsigned short*)(ws + 161472512);    // 18,612,224
  // total: 180,084,736

  {
    int total = M_ROWS * (D_MODEL / 4);
    convert_pad<<<(total + 255) / 256, 256, 0, stream>>>(hs, hsb, M_ROWS, M_ROWS, D_MODEL);
  }
  {
    int total = E_STR * (D_MODEL / 4);
    convert_pad<<<(total + 255) / 256, 256, 0, stream>>>(wqkv, wqkvb, E_QKV, E_STR, D_MODEL);
  }
  {
    int total = D_PAD * (D_MODEL / 4);
    convert_pad<<<(total + 255) / 256, 256, 0, stream>>>(wdense, wdb, D_MODEL, D_PAD, D_MODEL);
  }
  gemm128<<<dim3(16 * 37), 256, 0, stream>>>(hsb, wqkvb, fused, D_MODEL, 37, E_STR, E_QKV);
  {
    int total = NB * SEQ * 73 * 64;
    rope_extract<<<(total + 255) / 256, 256, 0, stream>>>(fused, qb, kb, vtb);
  }
  attn_kernel<<<dim3(8, NH, NB), 128, 0, stream>>>(qb, kb, vtb, attnb);
  gemm128<<<dim3(16 * 36), 256, 0, stream>>>(attnb, wdb, out, D_MODEL, 36, D_MODEL, D_MODEL);
}

// Round 12
// 441.731 us; speedup vs baseline: 1.4073x; 1.4073x over previous
//
#include <hip/hip_runtime.h>

#define D_MODEL 4544
#define E_QKV   4672     // D + 2*64
#define E_STR   4736     // fused row stride (37*128)
#define E_PAD2  4864     // QKV weight rows padded (19*256)
#define D_PAD   4608     // dense weight rows padded (18*256)
#define NH      71
#define SEQ     1024
#define NB      2
#define M_ROWS  2048     // NB*SEQ

typedef __bf16 bf16_t;
typedef bf16_t bf16x8 __attribute__((ext_vector_type(8)));
typedef float f32x4 __attribute__((ext_vector_type(4)));
typedef float f32x16 __attribute__((ext_vector_type(16)));
typedef unsigned u32x4 __attribute__((ext_vector_type(4)));

typedef __attribute__((address_space(1))) const void* gas_ptr;
typedef __attribute__((address_space(3))) void* las_ptr;

static __device__ __forceinline__ unsigned short f2bf(float f) {
  union { float f; unsigned u; } v; v.f = f;
  unsigned r = (v.u + 0x7fffu + ((v.u >> 16) & 1u)) >> 16;
  return (unsigned short)r;
}

static __device__ __forceinline__ unsigned cvtpk_bf16(float lo, float hi) {
  unsigned r;
  asm("v_cvt_pk_bf16_f32 %0, %1, %2" : "=v"(r) : "v"(lo), "v"(hi));
  return r;
}

static __device__ __forceinline__ float fast_exp2(float x) {
  float r;
  asm("v_exp_f32 %0, %1" : "=v"(r) : "v"(x));
  return r;
}

// merged convert: hs -> hsb [M_ROWS], wqkv -> wqkvb [E_PAD2 pad], wdense -> wdb [D_PAD pad]
__global__ void convert3(const float* __restrict__ hs, const float* __restrict__ wq,
                         const float* __restrict__ wd,
                         unsigned short* __restrict__ hsb, unsigned short* __restrict__ wqb,
                         unsigned short* __restrict__ wdb) {
  const int C4 = D_MODEL >> 2;   // 1136
  int idx = blockIdx.x * 256 + threadIdx.x;
  const int n1 = M_ROWS * C4;
  const int n2 = n1 + E_PAD2 * C4;
  const int n3 = n2 + D_PAD * C4;
  if (idx >= n3) return;
  const float* src; unsigned short* dst; int rows_src; int rel;
  if (idx < n1)      { src = hs; dst = hsb; rows_src = M_ROWS;  rel = idx; }
  else if (idx < n2) { src = wq; dst = wqb; rows_src = E_QKV;   rel = idx - n1; }
  else               { src = wd; dst = wdb; rows_src = D_MODEL; rel = idx - n2; }
  int row = rel / C4;
  int c4 = (rel - row * C4) << 2;
  ushort4 o;
  if (row < rows_src) {
    const float4 v = *(const float4*)(src + (size_t)row * D_MODEL + c4);
    o.x = f2bf(v.x); o.y = f2bf(v.y); o.z = f2bf(v.z); o.w = f2bf(v.w);
  } else {
    o.x = 0; o.y = 0; o.z = 0; o.w = 0;
  }
  *(ushort4*)(dst + (size_t)row * D_MODEL + c4) = o;
}

// ------- 256x256 GEMM, split-K=3, proven 4-phase 8-barrier schedule,
// ------- compute core = mfma_f32_32x32x16_bf16 (20% higher FLOP/cyc).
// LDS: buf b, op -> 16K-element region of 32 chunks (1 KiB each).
// Chunk (blk, ks) = rows blk*32..+31 x k ks*16..+15, lane-ordered:
// lane l -> (row blk*32+(l&31), k ks*16+(l>>5)*8). Every ds_read and
// global_load_lds is a dense contiguous 1 KiB wave access (conflict-free).
#define REG16(b_, op_) ((((b_) * 2 + (op_)) << 14))

#define STAGE2(b_, op_, ksp_, kt_) do {                                        \
  const unsigned short* _p = (op_) ? pB : pA;                                  \
  const int _k0 = ((kt_) << 6) + ((ksp_) << 5);                                \
  __builtin_amdgcn_global_load_lds((gas_ptr)(_p + _k0),                        \
      (las_ptr)(lds + REG16(b_, op_) + ((wave * 4 + (ksp_) * 2) << 9)), 16, 0, 0); \
  __builtin_amdgcn_global_load_lds((gas_ptr)(_p + _k0 + 16),                   \
      (las_ptr)(lds + REG16(b_, op_) + ((wave * 4 + (ksp_) * 2 + 1) << 9)), 16, 0, 0); \
} while (0)

#define LDA4(b_, ksp_, mq_) do {                                               \
  const unsigned short* _ab = lds + REG16(b_, 0);                              \
  _Pragma("unroll")                                                            \
  for (int _m = 0; _m < 2; ++_m)                                               \
    _Pragma("unroll")                                                          \
    for (int _ks = 0; _ks < 2; ++_ks)                                          \
      a[_m * 2 + _ks] = *(const bf16x8*)&_ab[                                  \
          (((wm * 4 + (mq_) * 2 + _m) * 4 + (ksp_) * 2 + _ks) << 9) + lane * 8]; \
} while (0)

#define LDB4(b_, ksp_) do {                                                    \
  const unsigned short* _bp = lds + REG16(b_, 1);                              \
  _Pragma("unroll")                                                            \
  for (int _n = 0; _n < 2; ++_n)                                               \
    _Pragma("unroll")                                                          \
    for (int _ks = 0; _ks < 2; ++_ks)                                          \
      bv[_n * 2 + _ks] = *(const bf16x8*)&_bp[                                 \
          (((wn * 2 + _n) * 4 + (ksp_) * 2 + _ks) << 9) + lane * 8];           \
} while (0)

#define MFMA8(mq_) do {                                                        \
  _Pragma("unroll")                                                            \
  for (int _m = 0; _m < 2; ++_m)                                               \
    _Pragma("unroll")                                                          \
    for (int _n = 0; _n < 2; ++_n)                                             \
      _Pragma("unroll")                                                        \
      for (int _ks = 0; _ks < 2; ++_ks)                                        \
        acc[(mq_) * 2 + _m][_n] = __builtin_amdgcn_mfma_f32_32x32x16_bf16(     \
            a[_m * 2 + _ks], bv[_n * 2 + _ks], acc[(mq_) * 2 + _m][_n], 0, 0, 0); \
} while (0)

__global__ __launch_bounds__(512, 2) void gemm256(
    const unsigned short* __restrict__ A,
    const unsigned short* __restrict__ B,
    float* __restrict__ C0, float* __restrict__ C1, float* __restrict__ C2,
    int K, int Ntiles, int ldc, int Nact, int chunk) {
  __shared__ __align__(16) unsigned short lds[65536];   // 128 KiB
  const int tid = threadIdx.x;
  const int wave = tid >> 6, lane = tid & 63;
  const int hi = lane >> 5;
  const int wm = wave >> 2, wn = wave & 3;
  const int nwg = gridDim.x;
  const int swz = (blockIdx.x & 7) * (nwg >> 3) + (blockIdx.x >> 3);
  const int tilesTot = 8 * Ntiles;
  const int kc = swz / tilesTot;
  const int tile = swz - kc * tilesTot;
  const int bm = tile / Ntiles, bn = tile - bm * Ntiles;
  const size_t bRow = (size_t)bm * 256, bCol = (size_t)bn * 256;
  const int NTtot = K >> 6;
  const int kb = kc * chunk;
  const int nt = (NTtot - kb < chunk) ? (NTtot - kb) : chunk;
  float* __restrict__ C = (kc == 0) ? C0 : ((kc == 1) ? C1 : C2);

  // per-lane staging base pointers (row part computed once)
  const unsigned short* pA = A + (bRow + (size_t)(wave * 32 + (lane & 31))) * K + hi * 8;
  const unsigned short* pB = B + (bCol + (size_t)(wave * 32 + (lane & 31))) * K + hi * 8;

  f32x16 acc[4][2] = {};

  STAGE2(0, 0, 0, kb); STAGE2(0, 1, 0, kb); STAGE2(0, 0, 1, kb); STAGE2(0, 1, 1, kb);
  STAGE2(1, 1, 0, kb + 1); STAGE2(1, 0, 0, kb + 1); STAGE2(1, 1, 1, kb + 1);
  asm volatile("s_waitcnt vmcnt(6)" ::: "memory");
  __builtin_amdgcn_s_barrier();

  for (int t = 0; t < nt; ++t) {
    const int b = t & 1;
    const int tn1 = kb + ((t + 1 < nt) ? t + 1 : 0);
    const int tn2 = kb + ((t + 2 < nt) ? t + 2 : 0);
    bf16x8 a[4], bv[4];
    // P1: (ksp0, m-quad 0); stage t+1's A-ks23 into other buf
    LDA4(b, 0, 0); LDB4(b, 0);
    STAGE2(b ^ 1, 0, 1, tn1);
    __builtin_amdgcn_s_barrier();
    asm volatile("s_waitcnt lgkmcnt(0)" ::: "memory");
    __builtin_amdgcn_s_setprio(1);
    MFMA8(0);
    __builtin_amdgcn_s_setprio(0);
    __builtin_amdgcn_s_barrier();
    // P2: (ksp0, m-quad 1); stage t+2's B-ks01
    LDA4(b, 0, 1);
    STAGE2(b, 1, 0, tn2);
    __builtin_amdgcn_s_barrier();
    asm volatile("s_waitcnt lgkmcnt(0)" ::: "memory");
    __builtin_amdgcn_s_setprio(1);
    MFMA8(1);
    __builtin_amdgcn_s_setprio(0);
    __builtin_amdgcn_s_barrier();
    // P3: (ksp1, m-quad 0); stage t+2's A-ks01
    LDA4(b, 1, 0); LDB4(b, 1);
    STAGE2(b, 0, 0, tn2);
    __builtin_amdgcn_s_barrier();
    asm volatile("s_waitcnt lgkmcnt(0)" ::: "memory");
    __builtin_amdgcn_s_setprio(1);
    MFMA8(0);
    __builtin_amdgcn_s_setprio(0);
    __builtin_amdgcn_s_barrier();
    // P4: (ksp1, m-quad 1); stage t+2's B-ks23; counted vmcnt
    LDA4(b, 1, 1);
    STAGE2(b, 1, 1, tn2);
    __builtin_amdgcn_s_barrier();
    asm volatile("s_waitcnt lgkmcnt(0)" ::: "memory");
    __builtin_amdgcn_s_setprio(1);
    MFMA8(1);
    __builtin_amdgcn_s_setprio(0);
    asm volatile("s_waitcnt vmcnt(6)" ::: "memory");
    __builtin_amdgcn_s_barrier();
  }
  asm volatile("s_waitcnt vmcnt(0)" ::: "memory");

#pragma unroll
  for (int am = 0; am < 4; ++am) {
#pragma unroll
    for (int nf = 0; nf < 2; ++nf) {
      int col = (int)bCol + wn * 64 + nf * 32 + (lane & 31);
      if (col < Nact) {
#pragma unroll
        for (int r = 0; r < 16; ++r) {
          size_t row = bRow + wm * 128 + am * 32 + (r & 3) + 8 * (r >> 2) + 4 * hi;
          C[row * ldc + col] = acc[am][nf][r];
        }
      }
    }
  }
}

// out = p0 + p1 + p2 (f32), float4-vectorized
__global__ void reduce3(const float* __restrict__ p0, const float* __restrict__ p1,
                        const float* __restrict__ p2, float* __restrict__ out, int total4) {
  int idx = blockIdx.x * 256 + threadIdx.x;
  if (idx >= total4) return;
  float4 a = *(const float4*)(p0 + (size_t)idx * 4);
  float4 b = *(const float4*)(p1 + (size_t)idx * 4);
  float4 cc = *(const float4*)(p2 + (size_t)idx * 4);
  float4 o;
  o.x = a.x + b.x + cc.x; o.y = a.y + b.y + cc.y;
  o.z = a.z + b.z + cc.z; o.w = a.w + b.w + cc.w;
  *(float4*)(out + (size_t)idx * 4) = o;
}

// fused partial-sum (np buffers) -> Qb (RoPE, *0.125*log2e), Kb (RoPE), VTb (V^T)
__global__ void rope_extract(const float* __restrict__ p0, const float* __restrict__ p1,
                             const float* __restrict__ p2, int np,
                             unsigned short* __restrict__ Qb,
                             unsigned short* __restrict__ Kb,
                             unsigned short* __restrict__ VTb) {
  int idx = blockIdx.x * 256 + threadIdx.x;
  const int total = NB * SEQ * 73 * 64;
  if (idx >= total) return;
  int d = idx & 63;
  int t = idx >> 6;
  int h = t % 73;  t /= 73;
  int l = t & (SEQ - 1);
  int n = t >> 10;
  const size_t base = ((size_t)(n * SEQ + l)) * E_STR + h * 64;
  float x = p0[base + d];
  if (np == 3) x += p1[base + d] + p2[base + d];
  if (h == 72) {
    VTb[((size_t)(n * 64 + d)) * SEQ + l] = f2bf(x);
    return;
  }
  int dh = d & 31;
  float inv = __expf(-(float)dh * (9.210340371976184f / 32.0f));
  float ang = (float)l * inv;
  float sn, cs;
  __sincosf(ang, &sn, &cs);
  int dx = (d < 32) ? d + 32 : d - 32;
  float xr = p0[base + dx];
  if (np == 3) xr += p1[base + dx] + p2[base + dx];
  float rh = (d < 32) ? -xr : xr;
  float out = x * cs + rh * sn;
  if (h == 71) {
    Kb[((size_t)(n * SEQ + l)) * 64 + d] = f2bf(out);
  } else {
    Qb[(((size_t)(n * NH + h)) * SEQ + l) * 64 + d] = f2bf(out * 0.1803368801111204f);
  }
}

// Swapped-QK^T flash MQA, per-wave causal pairing + K-prefetch + V-early-issue.
#define LOADK(dst_, ktv_) do {                                                 \
  _Pragma("unroll")                                                            \
  for (int _cc = 0; _cc < 4; ++_cc) {                                          \
    dst_[_cc]     = *(const bf16x8*)&kbase[(size_t)((ktv_) + c) * 64 + _cc * 16 + hi * 8];      \
    dst_[4 + _cc] = *(const bf16x8*)&kbase[(size_t)((ktv_) + 32 + c) * 64 + _cc * 16 + hi * 8]; \
  }                                                                            \
} while (0)

__global__ __launch_bounds__(128) void attn_kernel(
    const unsigned short* __restrict__ Qb,
    const unsigned short* __restrict__ Kb,
    const unsigned short* __restrict__ VTb,
    unsigned short* __restrict__ attnb) {
  const int h = blockIdx.y, n = blockIdx.z;
  const int wave = threadIdx.x >> 6, lane = threadIdx.x & 63;
  const int c = lane & 31, hi = lane >> 5;
  const int gw = blockIdx.x * 2 + wave;   // 0..15

  const unsigned short* kbase = Kb + (size_t)n * SEQ * 64;
  const unsigned short* vtbase = VTb + (size_t)n * 64 * SEQ;

  for (int pass = 0; pass < 2; ++pass) {
    const int tile = pass ? gw : (31 - gw);
    const int qrow0 = tile * 32;
    const int q = qrow0 + c;
    const int nk = qrow0 + 32;
    const unsigned short* qbase = Qb + (((size_t)(n * NH + h)) * SEQ + qrow0) * 64;

    bf16x8 qf[4];
#pragma unroll
    for (int cc = 0; cc < 4; ++cc)
      qf[cc] = *(const bf16x8*)&qbase[c * 64 + cc * 16 + hi * 8];

    f32x16 o0 = {}, o1 = {};
    float m_run = -1e30f, l_run = 0.f;

    bf16x8 kc[8], kn[8];
    LOADK(kc, 0);

    for (int kt = 0; kt < nk; kt += 64) {
      const bool more = (kt + 64) < nk;
      f32x16 s0 = {}, s1 = {};
#pragma unroll
      for (int cc = 0; cc < 4; ++cc) {
        s0 = __builtin_amdgcn_mfma_f32_32x32x16_bf16(kc[cc], qf[cc], s0, 0, 0, 0);
        s1 = __builtin_amdgcn_mfma_f32_32x32x16_bf16(kc[4 + cc], qf[cc], s1, 0, 0, 0);
      }
      if (more) LOADK(kn, kt + 64);
      bf16x8 vv0[4], vv1[4];
#pragma unroll
      for (int cg = 0; cg < 4; ++cg) {
        vv0[cg] = *(const bf16x8*)&vtbase[(size_t)c * SEQ + kt + cg * 16 + hi * 8];
        vv1[cg] = *(const bf16x8*)&vtbase[(size_t)(32 + c) * SEQ + kt + cg * 16 + hi * 8];
      }
      __builtin_amdgcn_sched_barrier(0);
      if (kt + 63 > qrow0) {
#pragma unroll
        for (int r = 0; r < 16; ++r) {
          const int key0 = kt + (r & 3) + 8 * (r >> 2) + 4 * hi;
          s0[r] = (key0 > q) ? -1e30f : s0[r];
          s1[r] = (key0 + 32 > q) ? -1e30f : s1[r];
        }
      }
      float tt[16];
#pragma unroll
      for (int r = 0; r < 16; ++r) tt[r] = fmaxf(s0[r], s1[r]);
#pragma unroll
      for (int st = 8; st > 0; st >>= 1)
#pragma unroll
        for (int r = 0; r < 8; ++r) if (r < st) tt[r] = fmaxf(tt[r], tt[r + st]);
      float mx = fmaxf(tt[0], __shfl_xor(tt[0], 32));
      const float mnew = fmaxf(m_run, mx);
      const float aa = fast_exp2(m_run - mnew);
#pragma unroll
      for (int r = 0; r < 16; ++r) {
        s0[r] = fast_exp2(s0[r] - mnew);
        s1[r] = fast_exp2(s1[r] - mnew);
      }
      float ps = 0.f;
#pragma unroll
      for (int r = 0; r < 16; ++r) ps += s0[r] + s1[r];
      ps += __shfl_xor(ps, 32);
      l_run = l_run * aa + ps;
      m_run = mnew;
#pragma unroll
      for (int r = 0; r < 16; ++r) { o0[r] *= aa; o1[r] *= aa; }

#pragma unroll
      for (int half = 0; half < 2; ++half) {
#pragma unroll
        for (int ccl = 0; ccl < 2; ++ccl) {
          const int cg = half * 2 + ccl;
          unsigned a0, a1, b0, b1;
          if (half == 0) {
            a0 = cvtpk_bf16(s0[8 * ccl + 0], s0[8 * ccl + 1]);
            a1 = cvtpk_bf16(s0[8 * ccl + 2], s0[8 * ccl + 3]);
            b0 = cvtpk_bf16(s0[8 * ccl + 4], s0[8 * ccl + 5]);
            b1 = cvtpk_bf16(s0[8 * ccl + 6], s0[8 * ccl + 7]);
          } else {
            a0 = cvtpk_bf16(s1[8 * ccl + 0], s1[8 * ccl + 1]);
            a1 = cvtpk_bf16(s1[8 * ccl + 2], s1[8 * ccl + 3]);
            b0 = cvtpk_bf16(s1[8 * ccl + 4], s1[8 * ccl + 5]);
            b1 = cvtpk_bf16(s1[8 * ccl + 6], s1[8 * ccl + 7]);
          }
          unsigned xa0 = __shfl_xor(a0, 32), xa1 = __shfl_xor(a1, 32);
          unsigned xb0 = __shfl_xor(b0, 32), xb1 = __shfl_xor(b1, 32);
          u32x4 fw;
          fw[0] = hi ? xb0 : a0;
          fw[1] = hi ? xb1 : a1;
          fw[2] = hi ? b0 : xa0;
          fw[3] = hi ? b1 : xa1;
          union { u32x4 u; bf16x8 b; } pf; pf.u = fw;
          o0 = __builtin_amdgcn_mfma_f32_32x32x16_bf16(vv0[cg], pf.b, o0, 0, 0, 0);
          o1 = __builtin_amdgcn_mfma_f32_32x32x16_bf16(vv1[cg], pf.b, o1, 0, 0, 0);
        }
      }
      if (more) {
#pragma unroll
        for (int cc = 0; cc < 8; ++cc) kc[cc] = kn[cc];
      }
    }

    const float inv = 1.0f / l_run;
    const size_t rowoff = (size_t)(n * SEQ + q) * D_MODEL + h * 64;
#pragma unroll
    for (int rr = 0; rr < 4; ++rr) {
      ushort4 w0, w1;
      w0.x = f2bf(o0[4 * rr + 0] * inv); w0.y = f2bf(o0[4 * rr + 1] * inv);
      w0.z = f2bf(o0[4 * rr + 2] * inv); w0.w = f2bf(o0[4 * rr + 3] * inv);
      w1.x = f2bf(o1[4 * rr + 0] * inv); w1.y = f2bf(o1[4 * rr + 1] * inv);
      w1.z = f2bf(o1[4 * rr + 2] * inv); w1.w = f2bf(o1[4 * rr + 3] * inv);
      *(ushort4*)&attnb[rowoff + 8 * rr + 4 * hi] = w0;
      *(ushort4*)&attnb[rowoff + 32 + 8 * rr + 4 * hi] = w1;
    }
  }
}

extern "C" void kernel_launch(void* const* d_in, const int* in_sizes, int n_in,
                              void* d_out, int out_size, void* d_ws, size_t ws_size,
                              hipStream_t stream) {
  const float* hs = (const float*)d_in[0];
  const float* wqkv = (const float*)d_in[1];
  const float* wdense = (const float*)d_in[2];
  float* out = (float*)d_out;
  char* ws = (char*)d_ws;

  unsigned short* hsb   = (unsigned short*)(ws + 0);            // 18,612,224
  unsigned short* wqkvb = (unsigned short*)(ws + 18612224);     // 44,208,128
  unsigned short* wdb   = (unsigned short*)(ws + 62820352);     // 41,881,600
  float*          fused = (float*)(ws + 104701952);             // 38,797,312
  unsigned short* qb    = (unsigned short*)(ws + 143499264);    // 18,612,224
  unsigned short* kb    = (unsigned short*)(ws + 162111488);    // 262,144
  unsigned short* vtb   = (unsigned short*)(ws + 162373632);    // 262,144
  unsigned short* attnb = (unsigned short*)(ws + 162635776);    // 18,612,224
  // base end: 181,248,000
  float* fusedE1 = (float*)(ws + 181248000);                    // 38,797,312
  float* fusedE2 = (float*)(ws + 220045312);                    // 38,797,312
  const int splitOK = (ws_size >= (size_t)258842624) ? 1 : 0;

  {
    const int C4 = D_MODEL >> 2;
    int total = (M_ROWS + E_PAD2 + D_PAD) * C4;
    convert3<<<(total + 255) / 256, 256, 0, stream>>>(hs, wqkv, wdense, hsb, wqkvb, wdb);
  }

  if (splitOK) {
    gemm256<<<dim3(8 * 19 * 3), 512, 0, stream>>>(hsb, wqkvb, fused, fusedE1, fusedE2,
                                                  D_MODEL, 19, E_STR, E_STR, 24);
  } else {
    gemm256<<<dim3(8 * 19), 512, 0, stream>>>(hsb, wqkvb, fused, fused, fused,
                                              D_MODEL, 19, E_STR, E_STR, 71);
  }
  {
    int total = NB * SEQ * 73 * 64;
    rope_extract<<<(total + 255) / 256, 256, 0, stream>>>(fused, fusedE1, fusedE2,
                                                          splitOK ? 3 : 1, qb, kb, vtb);
  }
  attn_kernel<<<dim3(8, NH, NB), 128, 0, stream>>>(qb, kb, vtb, attnb);
  if (splitOK) {
    float* p0 = (float*)(ws + 0);
    float* p1 = fused;
    float* p2 = fusedE1;
    gemm256<<<dim3(8 * 18 * 3), 512, 0, stream>>>(attnb, wdb, p0, p1, p2,
                                                  D_MODEL, 18, D_MODEL, D_MODEL, 24);
    int total4 = (M_ROWS * D_MODEL) / 4;
    reduce3<<<(total4 + 255) / 256, 256, 0, stream>>>(p0, p1, p2, out, total4);
  } else {
    gemm256<<<dim3(8 * 18), 512, 0, stream>>>(attnb, wdb, out, out, out,
                                              D_MODEL, 18, D_MODEL, D_MODEL, 71);
  }
}